// Round 2
// baseline (115.467 us; speedup 1.0000x reference)
//
#include <hip/hip_runtime.h>

// GraphAutoEncoder: one thread per graph (B=131072, N=8).
// Encoder (3->64->2) -> Gabriel graph on 2D latent -> GCN (algebraically
// reduced) -> mean-pool -> decoder column 1 (computed once, broadcast to 8).
//
// Algebraic reductions (exact in real arithmetic, ulp-level fp deviation):
//   norm@(latent@W1)        = (norm@latent)@W1          (aggregate 2-wide, not 32-wide)
//   mean_i(norm@Z + b)      = (colmean(norm))@Z + b     (h2 never materialized)
//   dec[:, :, 1] identical across nodes -> compute one scalar, broadcast x8.

__global__ __launch_bounds__(256, 2) void gae_kernel(
    const float* __restrict__ x,        // (B,8)
    const float* __restrict__ enc_w1,   // (3,64)
    const float* __restrict__ enc_b1,   // (64,)
    const float* __restrict__ enc_w2,   // (64,2)
    const float* __restrict__ enc_b2,   // (2,)
    const float* __restrict__ gcn1_w,   // (2,32)
    const float* __restrict__ gcn1_b,   // (32,)
    const float* __restrict__ gcn2_w,   // (32,32)
    const float* __restrict__ gcn2_b,   // (32,)
    const float* __restrict__ dec_w1,   // (32,64)
    const float* __restrict__ dec_b1,   // (64,)
    const float* __restrict__ dec_w2,   // (64,3)
    const float* __restrict__ dec_b2,   // (3,)
    float* __restrict__ out_rec,        // (B,8)
    float* __restrict__ out_lat,        // (B,8,2)
    int B)
{
    const int b = blockIdx.x * blockDim.x + threadIdx.x;
    if (b >= B) return;

    // ---- load x[b, 0..7] (two float4, coalesced 32B/lane) ----
    float xv[8];
    {
        const float4* xp = reinterpret_cast<const float4*>(x + (size_t)b * 8);
        float4 a = xp[0], c = xp[1];
        xv[0] = a.x; xv[1] = a.y; xv[2] = a.z; xv[3] = a.w;
        xv[4] = c.x; xv[5] = c.y; xv[6] = c.z; xv[7] = c.w;
    }

    // ---- encoder: latent[i] = relu(xp_i @ W1 + b1) @ W2 + b2 ----
    // xp_i = (0, x_i, i). h-outer runtime loop: weights are wave-uniform
    // s_loads hoisted once per h; 8 independent fma chains give ILP.
    float px[8], py[8];
    #pragma unroll
    for (int i = 0; i < 8; ++i) { px[i] = enc_b2[0]; py[i] = enc_b2[1]; }
    #pragma unroll 2
    for (int h = 0; h < 64; ++h) {
        const float wx = enc_w1[64 + h];    // W1[1][h]
        const float wi = enc_w1[128 + h];   // W1[2][h]
        const float bb = enc_b1[h];
        const float ux = enc_w2[2 * h + 0];
        const float uy = enc_w2[2 * h + 1];
        #pragma unroll
        for (int i = 0; i < 8; ++i) {
            float t = fmaf(xv[i], wx, fmaf((float)i, wi, bb));
            t = fmaxf(t, 0.0f);
            px[i] = fmaf(t, ux, px[i]);
            py[i] = fmaf(t, uy, py[i]);
        }
    }

    // ---- write latent output early (B,8,2) ----
    {
        float4* lo = reinterpret_cast<float4*>(out_lat + (size_t)b * 16);
        lo[0] = make_float4(px[0], py[0], px[1], py[1]);
        lo[1] = make_float4(px[2], py[2], px[3], py[3]);
        lo[2] = make_float4(px[4], py[4], px[5], py[5]);
        lo[3] = make_float4(px[6], py[6], px[7], py[7]);
    }

    // ---- Gabriel graph: a_hat row masks (bit j of m[i]); diag = self loop ----
    unsigned m[8];
    #pragma unroll
    for (int i = 0; i < 8; ++i) m[i] = 1u << i;
    {
        // No fma contraction here: the d2 < r2 compares are discrete decisions
        // and must mirror the reference's elementwise arithmetic. r2 is
        // computed per DIRECTION (r2[i][j] != r2[j][i] by ulps), matching the
        // reference's asymmetric adjacency.
        #pragma clang fp contract(off)
        #pragma unroll
        for (int i = 0; i < 8; ++i) {
            #pragma unroll
            for (int j = i + 1; j < 8; ++j) {
                float mx = (px[i] + px[j]) * 0.5f;
                float my = (py[i] + py[j]) * 0.5f;
                float dxi = px[i] - mx, dyi = py[i] - my;
                float r2i = dxi * dxi + dyi * dyi;   // radius^2 for (i,j)
                float dxj = px[j] - mx, dyj = py[j] - my;
                float r2j = dxj * dxj + dyj * dyj;   // radius^2 for (j,i)
                bool bi = false, bj = false;
                #pragma unroll
                for (int k = 0; k < 8; ++k) {
                    if (k == i || k == j) continue;
                    float dx = px[k] - mx, dy = py[k] - my;
                    float d2 = dx * dx + dy * dy;
                    bi = bi || (d2 < r2i);
                    bj = bj || (d2 < r2j);
                }
                m[i] |= bi ? 0u : (1u << j);
                m[j] |= bj ? 0u : (1u << i);
            }
        }
    }

    // ---- degrees, dinv = rsqrt(rowsum(a_hat)) ----
    // deg in {1..8}; v_rsq_f32 is <=1 ulp (reference itself uses lax.rsqrt).
    float dinv[8];
    #pragma unroll
    for (int i = 0; i < 8; ++i)
        dinv[i] = __builtin_amdgcn_rsqf((float)__popc(m[i]));

    // ---- norm @ latent -> (nx,ny); column means of norm -> cj ----
    float qx[8], qy[8];
    #pragma unroll
    for (int j = 0; j < 8; ++j) { qx[j] = dinv[j] * px[j]; qy[j] = dinv[j] * py[j]; }

    float nx[8], ny[8];
    #pragma unroll
    for (int i = 0; i < 8; ++i) {
        float sx = 0.0f, sy = 0.0f;
        #pragma unroll
        for (int j = 0; j < 8; ++j) {
            float co = (float)((m[i] >> j) & 1u);
            sx = fmaf(co, qx[j], sx);
            sy = fmaf(co, qy[j], sy);
        }
        nx[i] = dinv[i] * sx;
        ny[i] = dinv[i] * sy;
    }

    // cj_j = (1/8) * dinv_j * sum_i a_hat[i][j] * dinv_i  (COLUMN sums: the
    // reference adjacency is not forced symmetric, so index rows' bit j).
    float cj[8];
    #pragma unroll
    for (int j = 0; j < 8; ++j) {
        float s = 0.0f;
        #pragma unroll
        for (int i = 0; i < 8; ++i) {
            float co = (float)((m[i] >> j) & 1u);
            s = fmaf(co, dinv[i], s);
        }
        cj[j] = 0.125f * dinv[j] * s;
    }

    // ---- GCN1 + pooled projection: t_f = sum_i cj_i * relu(h1[i][f]) ----
    float t[32];
    #pragma unroll
    for (int f = 0; f < 32; ++f) t[f] = 0.0f;
    #pragma unroll
    for (int i = 0; i < 8; ++i) {
        #pragma unroll
        for (int f = 0; f < 32; ++f) {
            float h = fmaf(nx[i], gcn1_w[f], fmaf(ny[i], gcn1_w[32 + f], gcn1_b[f]));
            h = fmaxf(h, 0.0f);
            t[f] = fmaf(cj[i], h, t[f]);
        }
    }

    // ---- pooled_g = t @ gcn2_w + gcn2_b  (32 independent chains: ILP) ----
    float pooled[32];
    #pragma unroll
    for (int g = 0; g < 32; ++g) {
        float a = gcn2_b[g];
        #pragma unroll
        for (int f = 0; f < 32; ++f) a = fmaf(t[f], gcn2_w[f * 32 + g], a);
        pooled[g] = a;
    }

    // ---- decoder: out = relu(pooled @ dec_w1 + dec_b1) . dec_w2[:,1] + dec_b2[1] ----
    float outv = 0.0f;
    #pragma unroll
    for (int h = 0; h < 64; ++h) {
        float a = dec_b1[h];
        #pragma unroll
        for (int f = 0; f < 32; ++f) a = fmaf(pooled[f], dec_w1[f * 64 + h], a);
        outv = fmaf(fmaxf(a, 0.0f), dec_w2[h * 3 + 1], outv);
    }
    outv += dec_b2[1];

    // ---- write reconstructed (same value for all 8 nodes) ----
    {
        float4 r4 = make_float4(outv, outv, outv, outv);
        float4* ro = reinterpret_cast<float4*>(out_rec + (size_t)b * 8);
        ro[0] = r4;
        ro[1] = r4;
    }
}

extern "C" void kernel_launch(void* const* d_in, const int* in_sizes, int n_in,
                              void* d_out, int out_size, void* d_ws, size_t ws_size,
                              hipStream_t stream) {
    const float* x       = (const float*)d_in[0];
    const float* enc_w1  = (const float*)d_in[1];
    const float* enc_b1  = (const float*)d_in[2];
    const float* enc_w2  = (const float*)d_in[3];
    const float* enc_b2  = (const float*)d_in[4];
    const float* gcn1_w  = (const float*)d_in[5];
    const float* gcn1_b  = (const float*)d_in[6];
    const float* gcn2_w  = (const float*)d_in[7];
    const float* gcn2_b  = (const float*)d_in[8];
    const float* dec_w1  = (const float*)d_in[9];
    const float* dec_b1  = (const float*)d_in[10];
    const float* dec_w2  = (const float*)d_in[11];
    const float* dec_b2  = (const float*)d_in[12];

    const int B = in_sizes[0] / 8;
    float* out_rec = (float*)d_out;                 // (B,8)
    float* out_lat = out_rec + (size_t)B * 8;       // (B,8,2)

    const int threads = 256;
    const int blocks  = (B + threads - 1) / threads;
    gae_kernel<<<blocks, threads, 0, stream>>>(
        x, enc_w1, enc_b1, enc_w2, enc_b2,
        gcn1_w, gcn1_b, gcn2_w, gcn2_b,
        dec_w1, dec_b1, dec_w2, dec_b2,
        out_rec, out_lat, B);
}